// Round 4
// baseline (617.611 us; speedup 1.0000x reference)
//
#include <hip/hip_runtime.h>
#include <hip/hip_cooperative_groups.h>

namespace cg = cooperative_groups;

// ScatterGeneralAttention, MI355X.
// R3: (a) seg_fused: batch-issue all row loads before any reduce
//     (sched_barrier(0) fence) so ~10 HBM misses/wave overlap instead of
//     serializing; nontemporal store for the 102 MB attn output.
//     (b) fuse memset+compute_w+rank+scan123+scatter into ONE cooperative
//     kernel (512x256, co-residency-safe) -> 2 launches total.
// R2 kept: V read once, rows cached in VGPRs (CAP=16, static unroll).
// R1 kept: counting-sort by segment, no float atomics, attn written once.
// R0 kept: probs = (v.(W^T a) + b.a) * D^-0.5; softmax shift-invariance.

#define DIM 256
#define WAVE 64
#define CAP 16

typedef float f4 __attribute__((ext_vector_type(4)));

// One cooperative kernel: zero counts + compute wc, rank, chunk scan,
// block-sum scan, add-back, scatter perm. Assumes ceil(e/256) <= 512.
__global__ void __launch_bounds__(256, 2)
sort_coop_kernel(const int* __restrict__ idx,
                 const float* __restrict__ W,
                 const float* __restrict__ b,
                 const float* __restrict__ a,
                 float* __restrict__ wc,
                 int* __restrict__ counts,
                 int* __restrict__ offsets,
                 int* __restrict__ bsums,
                 int* __restrict__ rank,
                 int* __restrict__ perm,
                 int n, int e, int nb) {
    cg::grid_group grid = cg::this_grid();
    const int t = threadIdx.x;
    const int gtid = blockIdx.x * 256 + t;
    const int gsz = gridDim.x * 256;
    __shared__ int sm[512];

    // P0: zero counts; block 0 computes wc = W^T a and c = b.a
    for (int i = gtid; i < e; i += gsz) counts[i] = 0;
    if (blockIdx.x == 0) {
        float acc = 0.f;
        for (int j = 0; j < DIM; ++j) acc += a[j] * W[j * DIM + t];
        wc[t] = acc;
        if (t == 0) {
            float c = 0.f;
            for (int j = 0; j < DIM; ++j) c += b[j] * a[j];
            wc[DIM] = c;
        }
    }
    grid.sync();

    // P1: rank[i] = counts[idx[i]]++
    for (int i = gtid; i < n; i += gsz) rank[i] = atomicAdd(&counts[idx[i]], 1);
    grid.sync();

    // P2: per-256-chunk exclusive scan; chunk c -> block c (nb <= gridDim)
    for (int c = blockIdx.x; c < nb; c += gridDim.x) {
        const int g = c * 256 + t;
        const int x = (g < e) ? counts[g] : 0;
        sm[t] = x; __syncthreads();
        for (int d = 1; d < 256; d <<= 1) {
            const int v = (t >= d) ? sm[t - d] : 0; __syncthreads();
            sm[t] += v; __syncthreads();
        }
        if (g < e) offsets[g] = sm[t] - x;
        if (t == 255) bsums[c] = sm[255];
        __syncthreads();
    }
    grid.sync();

    // P3: block 0 scans bsums[nb] (nb <= 512; 2 elems/thread Hillis-Steele)
    if (blockIdx.x == 0) {
        const int x0 = (t < nb) ? bsums[t] : 0;
        const int x1 = (t + 256 < nb) ? bsums[t + 256] : 0;
        sm[t] = x0; sm[t + 256] = x1; __syncthreads();
        for (int d = 1; d < 512; d <<= 1) {
            const int v0 = (t >= d) ? sm[t - d] : 0;
            const int v1 = (t + 256 >= d) ? sm[t + 256 - d] : 0;
            __syncthreads();
            sm[t] += v0; sm[t + 256] += v1;
            __syncthreads();
        }
        if (t < nb) bsums[t] = sm[t] - x0;
        if (t + 256 < nb) bsums[t + 256] = sm[t + 256] - x1;
    }
    grid.sync();

    // P4: add block offsets; offsets[e] = n
    for (int c = blockIdx.x; c < nb; c += gridDim.x) {
        const int g = c * 256 + t;
        if (g < e) offsets[g] += bsums[c];
    }
    if (gtid == 0) offsets[e] = n;
    grid.sync();

    // P5: perm[offsets[seg] + rank[i]] = i
    for (int i = gtid; i < n; i += gsz) perm[offsets[idx[i]] + rank[i]] = i;
}

// One wave per segment, V read once: rows cached in registers (cnt <= CAP).
__global__ void seg_fused_kernel(const float4* __restrict__ v4,
                                 const int* __restrict__ perm,
                                 const float* __restrict__ wc,
                                 const int* __restrict__ offsets,
                                 float* __restrict__ scores,
                                 float* __restrict__ attn, int e) {
    const int lane = threadIdx.x & (WAVE - 1);
    const int s = (blockIdx.x * blockDim.x + threadIdx.x) >> 6;
    if (s >= e) return;
    const float4 wf = ((const float4*)wc)[lane];
    const float c = wc[DIM];
    const int base = offsets[s];
    const int cnt  = offsets[s + 1] - base;
    f4 acc = {0.f, 0.f, 0.f, 0.f};

    if (cnt > 0 && cnt <= CAP) {
        const int i_l = (lane < cnt) ? perm[base + lane] : 0;
        int idxs[CAP];
        #pragma unroll
        for (int t = 0; t < CAP; ++t) idxs[t] = __shfl(i_l, t, WAVE);
        float4 row[CAP];                        // static indices only -> VGPRs
        #pragma unroll
        for (int t = 0; t < CAP; ++t)
            if (t < cnt) row[t] = v4[(size_t)idxs[t] * (DIM / 4) + lane];
        __builtin_amdgcn_sched_barrier(0);      // keep all loads issued first
        float p[CAP];                           // wave-uniform after reduce
        #pragma unroll
        for (int t = 0; t < CAP; ++t) {
            if (t < cnt) {
                float pp = row[t].x * wf.x + row[t].y * wf.y
                         + row[t].z * wf.z + row[t].w * wf.w;
                #pragma unroll
                for (int off = 32; off; off >>= 1) pp += __shfl_xor(pp, off, WAVE);
                p[t] = __expf((pp + c) * 0.0625f);
            } else p[t] = 0.f;
        }
        float d = 0.f;
        #pragma unroll
        for (int t = 0; t < CAP; ++t) d += p[t];
        const float inv = 1.f / d;
        float myp = 0.f;                        // p[lane] with static indices
        #pragma unroll
        for (int t = 0; t < CAP; ++t) if (lane == t) myp = p[t];
        if (lane < cnt) scores[i_l] = myp * inv;
        #pragma unroll
        for (int t = 0; t < CAP; ++t) {
            if (t < cnt) {
                const float sc = p[t] * inv;
                acc[0] += sc * row[t].x; acc[1] += sc * row[t].y;
                acc[2] += sc * row[t].z; acc[3] += sc * row[t].w;
            }
        }
    } else if (cnt > CAP) {                     // rare tail: 2 passes, 2nd L2-hot
        float d = 0.f;
        for (int t = 0; t < cnt; ++t) {
            const int i = perm[base + t];
            const float4 vv = v4[(size_t)i * (DIM / 4) + lane];
            float pp = vv.x * wf.x + vv.y * wf.y + vv.z * wf.z + vv.w * wf.w;
            #pragma unroll
            for (int off = 32; off; off >>= 1) pp += __shfl_xor(pp, off, WAVE);
            d += __expf((pp + c) * 0.0625f);
        }
        const float inv = 1.f / d;
        for (int t = 0; t < cnt; ++t) {
            const int i = perm[base + t];
            const float4 vv = v4[(size_t)i * (DIM / 4) + lane];
            float pp = vv.x * wf.x + vv.y * wf.y + vv.z * wf.z + vv.w * wf.w;
            #pragma unroll
            for (int off = 32; off; off >>= 1) pp += __shfl_xor(pp, off, WAVE);
            const float sc = __expf((pp + c) * 0.0625f) * inv;
            if (lane == 0) scores[i] = sc;
            acc[0] += sc * vv.x; acc[1] += sc * vv.y;
            acc[2] += sc * vv.z; acc[3] += sc * vv.w;
        }
    }
    // attn row written exactly once; streaming, never re-read -> nontemporal
    __builtin_nontemporal_store(acc, (f4*)(attn + (size_t)s * DIM) + lane);
}

extern "C" void kernel_launch(void* const* d_in, const int* in_sizes, int n_in,
                              void* d_out, int out_size, void* d_ws, size_t ws_size,
                              hipStream_t stream) {
    const float* v   = (const float*)d_in[0];   // [N, 256]
    const int*   idx = (const int*)d_in[1];     // [N]
    const float* W   = (const float*)d_in[3];   // [256, 256]
    const float* b   = (const float*)d_in[4];   // [256]
    const float* a   = (const float*)d_in[5];   // [256]

    const int n = in_sizes[0] / DIM;            // 1,000,000
    const int e = (out_size - n) / DIM;         // 100,000
    const int nb = (e + 255) / 256;             // 391 <= 512

    float* scores = (float*)d_out;              // [N]
    float* attn   = (float*)d_out + n;          // [E, 256]

    // workspace: 512 + E + (E+2) + 512 + N + N words ~= 8.8 MB
    float* wc      = (float*)d_ws;
    int*   counts  = (int*)(wc + 512);          // [E]
    int*   offsets = counts + e;                // [E+1] (+1 pad)
    int*   bsums   = offsets + e + 2;           // [<=512]
    int*   rank    = bsums + 512;               // [N]
    int*   perm    = rank + n;                  // [N]

    void* args[] = {(void*)&idx, (void*)&W, (void*)&b, (void*)&a,
                    (void*)&wc, (void*)&counts, (void*)&offsets, (void*)&bsums,
                    (void*)&rank, (void*)&perm, (void*)&n, (void*)&e, (void*)&nb};
    hipLaunchCooperativeKernel((void*)sort_coop_kernel, dim3(512), dim3(256),
                               args, 0, stream);

    seg_fused_kernel<<<(e + 3) / 4, 256, 0, stream>>>((const float4*)v, perm, wc,
                                                      offsets, scores, attn, e);
}

// Round 5
// 326.202 us; speedup vs baseline: 1.8933x; 1.8933x over previous
//
#include <hip/hip_runtime.h>

// ScatterGeneralAttention, MI355X.
// R4: revert R3's cooperative kernel (grid.sync x5 across 8 XCDs caused the
//     618us regression) back to R2's 7-launch pipeline (known 364us). Two
//     isolated fixes on top:
//     (a) seg_fused tail (cnt>16, ~2.7% of segments): chunked batched loads
//         (16 misses in flight) instead of serial per-item loads; per-chunk
//         exp values stashed coalesced in the dead `rank` buffer.
//     (b) compute_w: 257 blocks + LDS tree reduce instead of 1 serial block.
// R2 kept: V read once, rows in VGPRs (CAP=16 static unroll), plain stores.
// R1 kept: counting-sort by segment, no float atomics, attn written once.
// R0 kept: probs = (v.(W^T a) + b.a) * D^-0.5; softmax shift-invariance.

#define DIM 256
#define WAVE 64
#define CAP 16

// grid 257 blocks x 256: block k<256 -> wc[k] = sum_j a[j]*W[j,k];
// block 256 -> wc[256] = sum_j a[j]*b[j].
__global__ void compute_w_kernel(const float* __restrict__ W,
                                 const float* __restrict__ b,
                                 const float* __restrict__ a,
                                 float* __restrict__ wc) {
    const int k = blockIdx.x, j = threadIdx.x;
    __shared__ float sm[256];
    sm[j] = (k < DIM) ? a[j] * W[j * DIM + k] : a[j] * b[j];
    __syncthreads();
    for (int d = 128; d; d >>= 1) {
        if (j < d) sm[j] += sm[j + d];
        __syncthreads();
    }
    if (j == 0) wc[k] = sm[0];
}

// rank[i] = counts[idx[i]]++
__global__ void rank_kernel(const int* __restrict__ idx,
                            int* __restrict__ counts,
                            int* __restrict__ rank, int n) {
    const int i = blockIdx.x * 256 + threadIdx.x;
    if (i < n) rank[i] = atomicAdd(&counts[idx[i]], 1);
}

// Hierarchical exclusive scan over counts[0..e) -> offsets (offsets[e]=n).
// Assumes ceil(e/256) <= 512 (e <= 131072; here e = 100000).
__global__ void scan1_kernel(const int* __restrict__ counts,
                             int* __restrict__ offsets,
                             int* __restrict__ bsums, int e) {
    __shared__ int s[256];
    const int t = threadIdx.x, g = blockIdx.x * 256 + t;
    const int x = (g < e) ? counts[g] : 0;
    s[t] = x; __syncthreads();
    for (int d = 1; d < 256; d <<= 1) {
        const int v = (t >= d) ? s[t - d] : 0; __syncthreads();
        s[t] += v; __syncthreads();
    }
    if (g < e) offsets[g] = s[t] - x;
    if (t == 255) bsums[blockIdx.x] = s[255];
}

__global__ void scan2_kernel(int* __restrict__ bsums, int nb) {
    __shared__ int s[512];
    const int t = threadIdx.x;
    const int x = (t < nb) ? bsums[t] : 0;
    s[t] = x; __syncthreads();
    for (int d = 1; d < 512; d <<= 1) {
        const int v = (t >= d) ? s[t - d] : 0; __syncthreads();
        s[t] += v; __syncthreads();
    }
    if (t < nb) bsums[t] = s[t] - x;
}

__global__ void scan3_kernel(int* __restrict__ offsets,
                             const int* __restrict__ bsums, int e, int n) {
    const int g = blockIdx.x * 256 + threadIdx.x;
    if (g < e) offsets[g] += bsums[blockIdx.x];
    if (g == 0) offsets[e] = n;
}

// perm[offsets[seg] + rank[i]] = i   (no atomics; ranks unique per segment)
__global__ void scatter_kernel(const int* __restrict__ idx,
                               const int* __restrict__ rank,
                               const int* __restrict__ offsets,
                               int* __restrict__ perm, int n) {
    const int i = blockIdx.x * 256 + threadIdx.x;
    if (i < n) perm[offsets[idx[i]] + rank[i]] = i;
}

// One wave per segment, V read once: rows cached in registers (cnt <= CAP);
// cnt > CAP tail chunked with batched loads, exp stash in exs (dead rank buf).
__global__ void seg_fused_kernel(const float4* __restrict__ v4,
                                 const int* __restrict__ perm,
                                 const float* __restrict__ wc,
                                 const int* __restrict__ offsets,
                                 float* __restrict__ exs,
                                 float* __restrict__ scores,
                                 float* __restrict__ attn, int e) {
    const int lane = threadIdx.x & (WAVE - 1);
    const int s = (blockIdx.x * blockDim.x + threadIdx.x) >> 6;
    if (s >= e) return;
    const float4 wf = ((const float4*)wc)[lane];
    const float c = wc[DIM];
    const int base = offsets[s];
    const int cnt  = offsets[s + 1] - base;
    float4 acc = make_float4(0.f, 0.f, 0.f, 0.f);

    if (cnt > 0 && cnt <= CAP) {
        const int i_l = (lane < cnt) ? perm[base + lane] : 0;
        int idxs[CAP];
        #pragma unroll
        for (int t = 0; t < CAP; ++t) idxs[t] = __shfl(i_l, t, WAVE);
        float4 row[CAP];                        // static indices only -> VGPRs
        #pragma unroll
        for (int t = 0; t < CAP; ++t)
            if (t < cnt) row[t] = v4[(size_t)idxs[t] * (DIM / 4) + lane];
        float p[CAP];                           // wave-uniform after reduce
        #pragma unroll
        for (int t = 0; t < CAP; ++t) {
            if (t < cnt) {
                float pp = row[t].x * wf.x + row[t].y * wf.y
                         + row[t].z * wf.z + row[t].w * wf.w;
                #pragma unroll
                for (int off = 32; off; off >>= 1) pp += __shfl_xor(pp, off, WAVE);
                p[t] = __expf((pp + c) * 0.0625f);
            } else p[t] = 0.f;
        }
        float d = 0.f;
        #pragma unroll
        for (int t = 0; t < CAP; ++t) d += p[t];
        const float inv = 1.f / d;
        float myp = 0.f;                        // p[lane] with static indices
        #pragma unroll
        for (int t = 0; t < CAP; ++t) if (lane == t) myp = p[t];
        if (lane < cnt) scores[i_l] = myp * inv;
        #pragma unroll
        for (int t = 0; t < CAP; ++t) {
            if (t < cnt) {
                const float sc = p[t] * inv;
                acc.x += sc * row[t].x; acc.y += sc * row[t].y;
                acc.z += sc * row[t].z; acc.w += sc * row[t].w;
            }
        }
    } else if (cnt > CAP) {
        // tail (~2.7%): chunks of CAP with batched loads; exp stash coalesced
        float d = 0.f;
        for (int st = 0; st < cnt; st += CAP) {
            const int m = min(CAP, cnt - st);
            const int i_l = (lane < m) ? perm[base + st + lane] : 0;
            int idxs[CAP];
            #pragma unroll
            for (int t = 0; t < CAP; ++t) idxs[t] = __shfl(i_l, t, WAVE);
            float4 row[CAP];
            #pragma unroll
            for (int t = 0; t < CAP; ++t)
                if (t < m) row[t] = v4[(size_t)idxs[t] * (DIM / 4) + lane];
            float p[CAP];
            #pragma unroll
            for (int t = 0; t < CAP; ++t) {
                if (t < m) {
                    float pp = row[t].x * wf.x + row[t].y * wf.y
                             + row[t].z * wf.z + row[t].w * wf.w;
                    #pragma unroll
                    for (int off = 32; off; off >>= 1) pp += __shfl_xor(pp, off, WAVE);
                    p[t] = __expf((pp + c) * 0.0625f);
                    d += p[t];
                }
            }
            float myp = 0.f;
            #pragma unroll
            for (int t = 0; t < CAP; ++t) if (lane == t) myp = p[t];
            if (lane < m) exs[base + st + lane] = myp;   // coalesced stash
        }
        const float inv = 1.f / d;
        for (int st = 0; st < cnt; st += CAP) {
            const int m = min(CAP, cnt - st);
            const int i_l = (lane < m) ? perm[base + st + lane] : 0;
            const float s_l = (lane < m) ? exs[base + st + lane] * inv : 0.f;
            if (lane < m) scores[i_l] = s_l;
            int idxs[CAP];
            #pragma unroll
            for (int t = 0; t < CAP; ++t) idxs[t] = __shfl(i_l, t, WAVE);
            float4 row[CAP];                    // re-gather, L2-hot
            #pragma unroll
            for (int t = 0; t < CAP; ++t)
                if (t < m) row[t] = v4[(size_t)idxs[t] * (DIM / 4) + lane];
            #pragma unroll
            for (int t = 0; t < CAP; ++t) {
                if (t < m) {
                    const float sc = __shfl(s_l, t, WAVE);
                    acc.x += sc * row[t].x; acc.y += sc * row[t].y;
                    acc.z += sc * row[t].z; acc.w += sc * row[t].w;
                }
            }
        }
    }
    ((float4*)(attn + (size_t)s * DIM))[lane] = acc;   // empty seg -> zeros
}

extern "C" void kernel_launch(void* const* d_in, const int* in_sizes, int n_in,
                              void* d_out, int out_size, void* d_ws, size_t ws_size,
                              hipStream_t stream) {
    const float* v   = (const float*)d_in[0];   // [N, 256]
    const int*   idx = (const int*)d_in[1];     // [N]
    const float* W   = (const float*)d_in[3];   // [256, 256]
    const float* b   = (const float*)d_in[4];   // [256]
    const float* a   = (const float*)d_in[5];   // [256]

    const int n = in_sizes[0] / DIM;            // 1,000,000
    const int e = (out_size - n) / DIM;         // 100,000
    const int nb = (e + 255) / 256;             // 391 <= 512

    float* scores = (float*)d_out;              // [N]
    float* attn   = (float*)d_out + n;          // [E, 256]

    // workspace: 512 + E + (E+2) + 512 + N + N words ~= 8.8 MB
    float* wc      = (float*)d_ws;
    int*   counts  = (int*)(wc + 512);          // [E]
    int*   offsets = counts + e;                // [E+1] (+1 pad)
    int*   bsums   = offsets + e + 2;           // [<=512]
    int*   rank    = bsums + 512;               // [N]; reused as exp stash later
    int*   perm    = rank + n;                  // [N]

    hipMemsetAsync(counts, 0, (size_t)e * sizeof(int), stream);
    compute_w_kernel<<<DIM + 1, 256, 0, stream>>>(W, b, a, wc);

    rank_kernel<<<(n + 255) / 256, 256, 0, stream>>>(idx, counts, rank, n);
    scan1_kernel<<<nb, 256, 0, stream>>>(counts, offsets, bsums, e);
    scan2_kernel<<<1, 512, 0, stream>>>(bsums, nb);
    scan3_kernel<<<nb, 256, 0, stream>>>(offsets, bsums, e, n);
    scatter_kernel<<<(n + 255) / 256, 256, 0, stream>>>(idx, rank, offsets, perm, n);

    seg_fused_kernel<<<(e + 3) / 4, 256, 0, stream>>>((const float4*)v, perm, wc,
                                                      offsets, (float*)rank,
                                                      scores, attn, e);
}

// Round 6
// 317.097 us; speedup vs baseline: 1.9477x; 1.0287x over previous
//
#include <hip/hip_runtime.h>

// ScatterGeneralAttention, MI355X.
// R5: "normalize last" in seg_fused — accumulate UNNORMALIZED acc_u = sum
//     exp_t * row_t and d = sum exp_t while rows stream; attn = acc_u / d at
//     the end. A row dies right after its own dot-reduce -> no row[16] cache
//     (was ~130 VGPR, ~8-12 waves/CU), now ~70-80 VGPR for 2x occupancy and
//     more gather misses in flight. Chunks of 8 rows pipelined; main path
//     covers cnt<=64 (Poisson(10) max ~30), serial fallback for correctness.
// R4 kept: parallel compute_w (257 blocks).
// R2/R1 kept: V read once, counting-sort, no float atomics, attn written once.
// R0 kept: probs = (v.(W^T a) + b.a) * D^-0.5; softmax shift-invariance.

#define DIM 256
#define WAVE 64

// grid 257 blocks x 256: block k<256 -> wc[k] = sum_j a[j]*W[j,k];
// block 256 -> wc[256] = sum_j a[j]*b[j].
__global__ void compute_w_kernel(const float* __restrict__ W,
                                 const float* __restrict__ b,
                                 const float* __restrict__ a,
                                 float* __restrict__ wc) {
    const int k = blockIdx.x, j = threadIdx.x;
    __shared__ float sm[256];
    sm[j] = (k < DIM) ? a[j] * W[j * DIM + k] : a[j] * b[j];
    __syncthreads();
    for (int d = 128; d; d >>= 1) {
        if (j < d) sm[j] += sm[j + d];
        __syncthreads();
    }
    if (j == 0) wc[k] = sm[0];
}

// rank[i] = counts[idx[i]]++
__global__ void rank_kernel(const int* __restrict__ idx,
                            int* __restrict__ counts,
                            int* __restrict__ rank, int n) {
    const int i = blockIdx.x * 256 + threadIdx.x;
    if (i < n) rank[i] = atomicAdd(&counts[idx[i]], 1);
}

// Hierarchical exclusive scan over counts[0..e) -> offsets (offsets[e]=n).
// Assumes ceil(e/256) <= 512 (e <= 131072; here e = 100000).
__global__ void scan1_kernel(const int* __restrict__ counts,
                             int* __restrict__ offsets,
                             int* __restrict__ bsums, int e) {
    __shared__ int s[256];
    const int t = threadIdx.x, g = blockIdx.x * 256 + t;
    const int x = (g < e) ? counts[g] : 0;
    s[t] = x; __syncthreads();
    for (int d = 1; d < 256; d <<= 1) {
        const int v = (t >= d) ? s[t - d] : 0; __syncthreads();
        s[t] += v; __syncthreads();
    }
    if (g < e) offsets[g] = s[t] - x;
    if (t == 255) bsums[blockIdx.x] = s[255];
}

__global__ void scan2_kernel(int* __restrict__ bsums, int nb) {
    __shared__ int s[512];
    const int t = threadIdx.x;
    const int x = (t < nb) ? bsums[t] : 0;
    s[t] = x; __syncthreads();
    for (int d = 1; d < 512; d <<= 1) {
        const int v = (t >= d) ? s[t - d] : 0; __syncthreads();
        s[t] += v; __syncthreads();
    }
    if (t < nb) bsums[t] = s[t] - x;
}

__global__ void scan3_kernel(int* __restrict__ offsets,
                             const int* __restrict__ bsums, int e, int n) {
    const int g = blockIdx.x * 256 + threadIdx.x;
    if (g < e) offsets[g] += bsums[blockIdx.x];
    if (g == 0) offsets[e] = n;
}

// perm[offsets[seg] + rank[i]] = i   (no atomics; ranks unique per segment)
__global__ void scatter_kernel(const int* __restrict__ idx,
                               const int* __restrict__ rank,
                               const int* __restrict__ offsets,
                               int* __restrict__ perm, int n) {
    const int i = blockIdx.x * 256 + threadIdx.x;
    if (i < n) perm[offsets[idx[i]] + rank[i]] = i;
}

// One wave per segment. Single streaming pass: chunks of 8 rows, unnormalized
// accumulate, divide by denom at the end. Rows never persist past their reduce.
__global__ void seg_fused_kernel(const float4* __restrict__ v4,
                                 const int* __restrict__ perm,
                                 const float* __restrict__ wc,
                                 const int* __restrict__ offsets,
                                 float* __restrict__ scores,
                                 float* __restrict__ attn, int e) {
    const int lane = threadIdx.x & (WAVE - 1);
    const int s = (blockIdx.x * blockDim.x + threadIdx.x) >> 6;
    if (s >= e) return;
    const float4 wf = ((const float4*)wc)[lane];
    const float c = wc[DIM];
    const int base = offsets[s];
    const int cnt  = offsets[s + 1] - base;
    float4 acc = make_float4(0.f, 0.f, 0.f, 0.f);

    if (cnt > 0 && cnt <= WAVE) {               // covers all segs here (max~30)
        const int i_l = (lane < cnt) ? perm[base + lane] : 0;
        float myp = 0.f, d = 0.f;
        #pragma unroll
        for (int ch = 0; ch < 8; ++ch) {
            const int st = ch * 8;
            if (st < cnt) {
                int ix8[8];
                #pragma unroll
                for (int t = 0; t < 8; ++t) ix8[t] = __shfl(i_l, st + t, WAVE);
                float4 row8[8];                 // 8 misses in flight per wave
                #pragma unroll
                for (int t = 0; t < 8; ++t)
                    if (st + t < cnt)
                        row8[t] = v4[(size_t)ix8[t] * (DIM / 4) + lane];
                #pragma unroll
                for (int t = 0; t < 8; ++t) {
                    if (st + t < cnt) {
                        float pp = row8[t].x * wf.x + row8[t].y * wf.y
                                 + row8[t].z * wf.z + row8[t].w * wf.w;
                        #pragma unroll
                        for (int off = 32; off; off >>= 1)
                            pp += __shfl_xor(pp, off, WAVE);
                        const float pe = __expf((pp + c) * 0.0625f);
                        d += pe;
                        acc.x += pe * row8[t].x; acc.y += pe * row8[t].y;
                        acc.z += pe * row8[t].z; acc.w += pe * row8[t].w;
                        if (lane == st + t) myp = pe;   // static lane-match
                    }
                }
            }
        }
        const float inv = 1.f / d;
        if (lane < cnt) scores[i_l] = myp * inv;
        acc.x *= inv; acc.y *= inv; acc.z *= inv; acc.w *= inv;
    } else if (cnt > WAVE) {                    // correctness-only fallback
        float d = 0.f;
        for (int t = 0; t < cnt; ++t) {
            const int i = perm[base + t];
            const float4 vv = v4[(size_t)i * (DIM / 4) + lane];
            float pp = vv.x * wf.x + vv.y * wf.y + vv.z * wf.z + vv.w * wf.w;
            #pragma unroll
            for (int off = 32; off; off >>= 1) pp += __shfl_xor(pp, off, WAVE);
            const float pe = __expf((pp + c) * 0.0625f);
            d += pe;
            acc.x += pe * vv.x; acc.y += pe * vv.y;
            acc.z += pe * vv.z; acc.w += pe * vv.w;
        }
        const float inv = 1.f / d;
        for (int t = 0; t < cnt; ++t) {         // recompute scores, L2/L3-hot
            const int i = perm[base + t];
            const float4 vv = v4[(size_t)i * (DIM / 4) + lane];
            float pp = vv.x * wf.x + vv.y * wf.y + vv.z * wf.z + vv.w * wf.w;
            #pragma unroll
            for (int off = 32; off; off >>= 1) pp += __shfl_xor(pp, off, WAVE);
            if (lane == 0) scores[i] = __expf((pp + c) * 0.0625f) * inv;
        }
        acc.x *= inv; acc.y *= inv; acc.z *= inv; acc.w *= inv;
    }
    ((float4*)(attn + (size_t)s * DIM))[lane] = acc;   // empty seg -> zeros
}

extern "C" void kernel_launch(void* const* d_in, const int* in_sizes, int n_in,
                              void* d_out, int out_size, void* d_ws, size_t ws_size,
                              hipStream_t stream) {
    const float* v   = (const float*)d_in[0];   // [N, 256]
    const int*   idx = (const int*)d_in[1];     // [N]
    const float* W   = (const float*)d_in[3];   // [256, 256]
    const float* b   = (const float*)d_in[4];   // [256]
    const float* a   = (const float*)d_in[5];   // [256]

    const int n = in_sizes[0] / DIM;            // 1,000,000
    const int e = (out_size - n) / DIM;         // 100,000
    const int nb = (e + 255) / 256;             // 391 <= 512

    float* scores = (float*)d_out;              // [N]
    float* attn   = (float*)d_out + n;          // [E, 256]

    // workspace: 512 + E + (E+2) + 512 + N + N words ~= 8.8 MB
    float* wc      = (float*)d_ws;
    int*   counts  = (int*)(wc + 512);          // [E]
    int*   offsets = counts + e;                // [E+1] (+1 pad)
    int*   bsums   = offsets + e + 2;           // [<=512]
    int*   rank    = bsums + 512;               // [N]
    int*   perm    = rank + n;                  // [N]

    hipMemsetAsync(counts, 0, (size_t)e * sizeof(int), stream);
    compute_w_kernel<<<DIM + 1, 256, 0, stream>>>(W, b, a, wc);

    rank_kernel<<<(n + 255) / 256, 256, 0, stream>>>(idx, counts, rank, n);
    scan1_kernel<<<nb, 256, 0, stream>>>(counts, offsets, bsums, e);
    scan2_kernel<<<1, 512, 0, stream>>>(bsums, nb);
    scan3_kernel<<<nb, 256, 0, stream>>>(offsets, bsums, e, n);
    scatter_kernel<<<(n + 255) / 256, 256, 0, stream>>>(idx, rank, offsets, perm, n);

    seg_fused_kernel<<<(e + 3) / 4, 256, 0, stream>>>((const float4*)v, perm, wc,
                                                      offsets, scores, attn, e);
}

// Round 8
// 284.354 us; speedup vs baseline: 2.1720x; 1.1152x over previous
//
#include <hip/hip_runtime.h>

// ScatterGeneralAttention, MI355X.
// R7 = R6 with compile fix: __builtin_nontemporal_* requires a clang vector
//     type, not HIP_vector_type. Use ext_vector_type(4) float (f4) for all
//     V loads and attn stores.
// R6: (a) nontemporal V loads + attn stores (zero-reuse streams; stop evicting
//         L2-resident perm/offsets/scores), (b) software-pipeline the row
//         chunks (prefetch next 8 rows before computing current 8), (c) merge
//         compute_w into rank_kernel (one launch fewer).
// R5 kept: normalize-last streaming accumulate (no row cache past reduce).
// R2/R1: V read once, counting-sort, no float atomics, attn written once.
// R0: probs = (v.(W^T a) + b.a) * D^-0.5; softmax shift-invariance.

#define DIM 256
#define WAVE 64

typedef float f4 __attribute__((ext_vector_type(4)));

// blocks 0..DIM: wc[k] = sum_j a[j]*W[j,k] (block DIM -> b.a);
// blocks DIM+1..: rank[i] = counts[idx[i]]++
__global__ void cw_rank_kernel(const float* __restrict__ W,
                               const float* __restrict__ b,
                               const float* __restrict__ a,
                               float* __restrict__ wc,
                               const int* __restrict__ idx,
                               int* __restrict__ counts,
                               int* __restrict__ rank, int n) {
    const int t = threadIdx.x;
    if (blockIdx.x <= DIM) {
        const int k = blockIdx.x;
        __shared__ float sm[256];
        sm[t] = (k < DIM) ? a[t] * W[t * DIM + k] : a[t] * b[t];
        __syncthreads();
        for (int d = 128; d; d >>= 1) {
            if (t < d) sm[t] += sm[t + d];
            __syncthreads();
        }
        if (t == 0) wc[k] = sm[0];
    } else {
        const int i = (blockIdx.x - DIM - 1) * 256 + t;
        if (i < n) rank[i] = atomicAdd(&counts[idx[i]], 1);
    }
}

// Hierarchical exclusive scan over counts[0..e) -> offsets (offsets[e]=n).
// Assumes ceil(e/256) <= 512 (e <= 131072; here e = 100000).
__global__ void scan1_kernel(const int* __restrict__ counts,
                             int* __restrict__ offsets,
                             int* __restrict__ bsums, int e) {
    __shared__ int s[256];
    const int t = threadIdx.x, g = blockIdx.x * 256 + t;
    const int x = (g < e) ? counts[g] : 0;
    s[t] = x; __syncthreads();
    for (int d = 1; d < 256; d <<= 1) {
        const int v = (t >= d) ? s[t - d] : 0; __syncthreads();
        s[t] += v; __syncthreads();
    }
    if (g < e) offsets[g] = s[t] - x;
    if (t == 255) bsums[blockIdx.x] = s[255];
}

__global__ void scan2_kernel(int* __restrict__ bsums, int nb) {
    __shared__ int s[512];
    const int t = threadIdx.x;
    const int x = (t < nb) ? bsums[t] : 0;
    s[t] = x; __syncthreads();
    for (int d = 1; d < 512; d <<= 1) {
        const int v = (t >= d) ? s[t - d] : 0; __syncthreads();
        s[t] += v; __syncthreads();
    }
    if (t < nb) bsums[t] = s[t] - x;
}

__global__ void scan3_kernel(int* __restrict__ offsets,
                             const int* __restrict__ bsums, int e, int n) {
    const int g = blockIdx.x * 256 + threadIdx.x;
    if (g < e) offsets[g] += bsums[blockIdx.x];
    if (g == 0) offsets[e] = n;
}

// perm[offsets[seg] + rank[i]] = i   (no atomics; ranks unique per segment)
__global__ void scatter_kernel(const int* __restrict__ idx,
                               const int* __restrict__ rank,
                               const int* __restrict__ offsets,
                               int* __restrict__ perm, int n) {
    const int i = blockIdx.x * 256 + threadIdx.x;
    if (i < n) perm[offsets[idx[i]] + rank[i]] = i;
}

// One wave per segment. Streaming normalize-last accumulate; chunks of 8 rows
// software-pipelined (prefetch next chunk); NT loads/stores on V/attn.
__global__ void seg_fused_kernel(const f4* __restrict__ v4,
                                 const int* __restrict__ perm,
                                 const float* __restrict__ wc,
                                 const int* __restrict__ offsets,
                                 float* __restrict__ scores,
                                 float* __restrict__ attn, int e) {
    const int lane = threadIdx.x & (WAVE - 1);
    const int s = (blockIdx.x * blockDim.x + threadIdx.x) >> 6;
    if (s >= e) return;
    const f4 wf = ((const f4*)wc)[lane];
    const float c = wc[DIM];
    const int base = offsets[s];
    const int cnt  = offsets[s + 1] - base;
    f4 acc = {0.f, 0.f, 0.f, 0.f};

    if (cnt > 0 && cnt <= WAVE) {               // covers all segs here (max~30)
        const int i_l = (lane < cnt) ? perm[base + lane] : 0;
        float myp = 0.f, d = 0.f;
        const int nch = (cnt + 7) >> 3;
        f4 cur[8], nxt[8];
        #pragma unroll
        for (int t = 0; t < 8; ++t)             // load chunk 0
            if (t < cnt)
                cur[t] = __builtin_nontemporal_load(
                    v4 + (size_t)__shfl(i_l, t, WAVE) * (DIM / 4) + lane);
        for (int ch = 0; ch < nch; ++ch) {
            const int st = ch * 8;
            if (ch + 1 < nch) {                 // prefetch chunk ch+1
                const int st2 = st + 8;
                #pragma unroll
                for (int t = 0; t < 8; ++t)
                    if (st2 + t < cnt)
                        nxt[t] = __builtin_nontemporal_load(
                            v4 + (size_t)__shfl(i_l, st2 + t, WAVE) * (DIM / 4) + lane);
            }
            #pragma unroll
            for (int t = 0; t < 8; ++t) {
                if (st + t < cnt) {
                    float pp = cur[t].x * wf.x + cur[t].y * wf.y
                             + cur[t].z * wf.z + cur[t].w * wf.w;
                    #pragma unroll
                    for (int off = 32; off; off >>= 1)
                        pp += __shfl_xor(pp, off, WAVE);
                    const float pe = __expf((pp + c) * 0.0625f);
                    d += pe;
                    acc.x += pe * cur[t].x; acc.y += pe * cur[t].y;
                    acc.z += pe * cur[t].z; acc.w += pe * cur[t].w;
                    if (lane == st + t) myp = pe;   // wave-uniform pe
                }
            }
            #pragma unroll
            for (int t = 0; t < 8; ++t) cur[t] = nxt[t];
        }
        const float inv = 1.f / d;
        if (lane < cnt) scores[i_l] = myp * inv;
        acc.x *= inv; acc.y *= inv; acc.z *= inv; acc.w *= inv;
    } else if (cnt > WAVE) {                    // correctness-only fallback
        float d = 0.f;
        for (int t = 0; t < cnt; ++t) {
            const int i = perm[base + t];
            const f4 vv = v4[(size_t)i * (DIM / 4) + lane];
            float pp = vv.x * wf.x + vv.y * wf.y + vv.z * wf.z + vv.w * wf.w;
            #pragma unroll
            for (int off = 32; off; off >>= 1) pp += __shfl_xor(pp, off, WAVE);
            const float pe = __expf((pp + c) * 0.0625f);
            d += pe;
            acc.x += pe * vv.x; acc.y += pe * vv.y;
            acc.z += pe * vv.z; acc.w += pe * vv.w;
        }
        const float inv = 1.f / d;
        for (int t = 0; t < cnt; ++t) {         // recompute scores, L2/L3-hot
            const int i = perm[base + t];
            const f4 vv = v4[(size_t)i * (DIM / 4) + lane];
            float pp = vv.x * wf.x + vv.y * wf.y + vv.z * wf.z + vv.w * wf.w;
            #pragma unroll
            for (int off = 32; off; off >>= 1) pp += __shfl_xor(pp, off, WAVE);
            if (lane == 0) scores[i] = __expf((pp + c) * 0.0625f) * inv;
        }
        acc.x *= inv; acc.y *= inv; acc.z *= inv; acc.w *= inv;
    }
    // attn row written exactly once, never re-read -> bypass L2 allocate
    __builtin_nontemporal_store(acc, (f4*)(attn + (size_t)s * DIM) + lane);
}

extern "C" void kernel_launch(void* const* d_in, const int* in_sizes, int n_in,
                              void* d_out, int out_size, void* d_ws, size_t ws_size,
                              hipStream_t stream) {
    const float* v   = (const float*)d_in[0];   // [N, 256]
    const int*   idx = (const int*)d_in[1];     // [N]
    const float* W   = (const float*)d_in[3];   // [256, 256]
    const float* b   = (const float*)d_in[4];   // [256]
    const float* a   = (const float*)d_in[5];   // [256]

    const int n = in_sizes[0] / DIM;            // 1,000,000
    const int e = (out_size - n) / DIM;         // 100,000
    const int nb = (e + 255) / 256;             // 391 <= 512

    float* scores = (float*)d_out;              // [N]
    float* attn   = (float*)d_out + n;          // [E, 256]

    // workspace: 512 + E + (E+2) + 512 + N + N words ~= 8.8 MB
    float* wc      = (float*)d_ws;
    int*   counts  = (int*)(wc + 512);          // [E]
    int*   offsets = counts + e;                // [E+1] (+1 pad)
    int*   bsums   = offsets + e + 2;           // [<=512]
    int*   rank    = bsums + 512;               // [N]
    int*   perm    = rank + n;                  // [N]

    hipMemsetAsync(counts, 0, (size_t)e * sizeof(int), stream);
    cw_rank_kernel<<<DIM + 1 + (n + 255) / 256, 256, 0, stream>>>(
        W, b, a, wc, idx, counts, rank, n);
    scan1_kernel<<<nb, 256, 0, stream>>>(counts, offsets, bsums, e);
    scan2_kernel<<<1, 512, 0, stream>>>(bsums, nb);
    scan3_kernel<<<nb, 256, 0, stream>>>(offsets, bsums, e, n);
    scatter_kernel<<<(n + 255) / 256, 256, 0, stream>>>(idx, rank, offsets, perm, n);

    seg_fused_kernel<<<(e + 3) / 4, 256, 0, stream>>>((const f4*)v, perm, wc,
                                                      offsets, scores, attn, e);
}